// Round 2
// baseline (643.838 us; speedup 1.0000x reference)
//
#include <hip/hip_runtime.h>
#include <hip/hip_bf16.h>

#define NROWS 8192
#define DDIM 768

typedef short short8 __attribute__((ext_vector_type(8)));   // 8 x bf16 (4 VGPRs)
typedef float floatx4 __attribute__((ext_vector_type(4)));  // MFMA C/D
typedef float f4 __attribute__((ext_vector_type(4)));
#define TSTRIDE 132   // transpose LDS row stride (floats): 2-way banks, 16B aligned

// ---------------------------------------------------------------------------
// Kernel 1: row-normalize features (fp32 in) -> bf16 normalized rows
// ---------------------------------------------------------------------------
__global__ __launch_bounds__(256) void normalize_k(const float* __restrict__ f,
                                                   __hip_bfloat16* __restrict__ fn) {
    const int row = blockIdx.x;
    const int t = threadIdx.x;
    const float* fr = f + (size_t)row * DDIM;
    float v0 = fr[t];
    float v1 = fr[t + 256];
    float v2 = fr[t + 512];
    float ss = v0 * v0 + v1 * v1 + v2 * v2;
#pragma unroll
    for (int m = 32; m; m >>= 1) ss += __shfl_xor(ss, m, 64);
    __shared__ float wsum[4];
    if ((t & 63) == 0) wsum[t >> 6] = ss;
    __syncthreads();
    float tot = wsum[0] + wsum[1] + wsum[2] + wsum[3];
    float inv = 1.0f / fmaxf(sqrtf(tot), 1e-8f);
    __hip_bfloat16* o = fn + (size_t)row * DDIM;
    o[t]       = __float2bfloat16(v0 * inv);
    o[t + 256] = __float2bfloat16(v1 * inv);
    o[t + 512] = __float2bfloat16(v2 * inv);
}

// ---------------------------------------------------------------------------
// Kernel 2: SYMMETRIC bf16 GEMM (s = 10 * fn fn^T) + fused mask reductions.
// R10: mask streaming fused into the K-loop. The 536 MB HBM mask stream was
// phase-serialized into the epilogue (HBM idle during the whole K-loop ->
// 2.3 of 6.3 TB/s). Now: per K-iter, DMA 3 float4 mask quads per thread into
// a 12 KB LDS slot (same barrier discipline as fn staging) and pack each
// element to 1 bit (masks are exactly 0.0/1.0) into 4 per-thread uint64s.
// Epilogues consume bits -> pure VALU/LDS, arithmetic order unchanged.
// K-loop reverted to the R8 single-buffer sync structure (dbuf gained 0).
// ---------------------------------------------------------------------------
__global__ __launch_bounds__(256, 4) void ntxent_main(
        const __hip_bfloat16* __restrict__ fn,
        const float* __restrict__ pmask, const float* __restrict__ nmask,
        float* __restrict__ negG, float* __restrict__ sG,
        float* __restrict__ pG) {
    __shared__ __align__(16) char smem[28672];   // fn 16384 + mask slot 12288
    __hip_bfloat16* Is = (__hip_bfloat16*)smem;             // [128*32] bf16
    __hip_bfloat16* Js = Is + 128 * 32;
    char* maskLds = smem + 16384;                           // [3*256*16B]
    float* T = (float*)smem;                                // mirror transpose alias

    const int t = threadIdx.x;
    const int lane = t & 63;
    const int wv = t >> 6;
    const int wm = wv & 1;           // wave's j-half
    const int wn = wv >> 1;          // wave's i-half
    const int q  = lane >> 4;
    const int cl = lane & 15;

    // XCD-chunked swizzle (2080 = 8*260, bijective)
    const int bt0 = blockIdx.x;
    const int bt = (bt0 & 7) * 260 + (bt0 >> 3);

    // triangular decode: block bt -> (c, r) with c <= r
    int r = (int)((sqrtf(8.0f * (float)bt + 1.0f) - 1.0f) * 0.5f);
    while ((r + 1) * (r + 2) / 2 <= bt) ++r;
    while (r * (r + 1) / 2 > bt) --r;
    const int c = bt - r * (r + 1) / 2;
    const int rowBase = c * 128;     // i-tile
    const int colBase = r * 128;     // j-tile
    const bool offDiag = (c != r);

    const int rdSw = ((q ^ ((cl >> 1) & 3)) << 4);

    floatx4 acc[4][4];            // [mf (j)][nf (i)]
#pragma unroll
    for (int mf = 0; mf < 4; ++mf)
#pragma unroll
        for (int nf = 0; nf < 4; ++nf)
            acc[mf][nf] = (floatx4){0.f, 0.f, 0.f, 0.f};

    // per-thread mask bits: direct (64) + mirror (64), pos & neg sides
    unsigned long long pD = 0ull, nD = 0ull, pM = 0ull, nM = 0ull;

    for (int kt = 0; kt < 24; ++kt) {
        const int k0 = kt * 32;
        __syncthreads();   // previous iter's readers done with Is/Js/maskLds

        // ---- mask DMA first (HBM, slowest): 3 quads/thread, qq = kt*3+ql ----
#pragma unroll
        for (int ql = 0; ql < 3; ++ql) {
            const int qq = kt * 3 + ql;
            if (qq >= 64) break;                      // uniform
            const bool mir = (qq >= 32);
            if (mir && !offDiag) continue;            // uniform
            const bool isN = (qq & 1);
            const float* mp = isN ? nmask : pmask;
            int row, col;
            if (!mir) {
                const int nf = qq >> 3, mf = (qq >> 1) & 3;
                row = rowBase + wn * 64 + nf * 16 + cl;
                col = colBase + wm * 64 + q * 4 + mf * 16;
            } else {
                const int m2 = qq - 32, st = m2 >> 3, u = (m2 >> 1) & 3;
                row = colBase + st * 32 + (t >> 3);
                col = rowBase + (t & 7) * 16 + u * 4;
            }
            const float* src = mp + (size_t)row * NROWS + col;
            __builtin_amdgcn_global_load_lds(
                (const __attribute__((address_space(1))) void*)src,
                (__attribute__((address_space(3))) void*)(maskLds + (ql * 256 + t) * 16),
                16, 0, 0);
        }

        // ---- fn staging (L2/L3-resident) ----
#pragma unroll
        for (int it = 0; it < 2; ++it) {
            const int s = it * 256 + t;              // 16B slot 0..511
            const int rr = s >> 2;
            const int cg = (s & 3) ^ ((rr >> 1) & 3); // swizzled src chunk
            const __hip_bfloat16* ga = fn + (size_t)(rowBase + rr) * DDIM + k0 + cg * 8;
            const __hip_bfloat16* gb = fn + (size_t)(colBase + rr) * DDIM + k0 + cg * 8;
            __builtin_amdgcn_global_load_lds(
                (const __attribute__((address_space(1))) void*)ga,
                (__attribute__((address_space(3))) void*)((char*)Is + s * 16), 16, 0, 0);
            __builtin_amdgcn_global_load_lds(
                (const __attribute__((address_space(1))) void*)gb,
                (__attribute__((address_space(3))) void*)((char*)Js + s * 16), 16, 0, 0);
        }
        __syncthreads();   // all DMA visible

        // ---- MFMA compute ----
        short8 jf[4], if_[4];
#pragma unroll
        for (int mf = 0; mf < 4; ++mf) {
            const int rr = wm * 64 + mf * 16 + cl;
            jf[mf] = *(const short8*)((const char*)Js + rr * 64 + rdSw);
        }
#pragma unroll
        for (int nf = 0; nf < 4; ++nf) {
            const int rr = wn * 64 + nf * 16 + cl;
            if_[nf] = *(const short8*)((const char*)Is + rr * 64 + rdSw);
        }
#pragma unroll
        for (int mf = 0; mf < 4; ++mf)
#pragma unroll
            for (int nf = 0; nf < 4; ++nf)
                acc[mf][nf] = __builtin_amdgcn_mfma_f32_16x16x32_bf16(
                    jf[mf], if_[nf], acc[mf][nf], 0, 0, 0);

        // ---- pack this iter's mask quads into bits (reads maskLds) ----
#pragma unroll
        for (int ql = 0; ql < 3; ++ql) {
            const int qq = kt * 3 + ql;
            if (qq >= 64) break;
            const bool mir = (qq >= 32);
            if (mir && !offDiag) continue;
            const f4 m4 = *(const f4*)(maskLds + (ql * 256 + t) * 16);
            const int mq = mir ? qq - 32 : qq;
            const int bb = ((mq >> 3) << 4) | (((mq >> 1) & 3) << 2);
            unsigned long long add = 0ull;
#pragma unroll
            for (int e = 0; e < 4; ++e)
                add |= (m4[e] > 0.5f) ? (1ull << (bb + e)) : 0ull;
            const bool isN = (qq & 1);
            if (!mir) { if (!isN) pD |= add; else nD |= add; }
            else      { if (!isN) pM |= add; else nM |= add; }
        }
    }

    // ---- direct epilogue (rows i, mask[i][j]) -- masks from bits ----
    const int col64 = colBase + wm * 64;
    const int jb0 = col64 + q * 4;
#pragma unroll
    for (int nf = 0; nf < 4; ++nf) {
        const int grow = rowBase + wn * 64 + nf * 16 + cl;
        float aN = 0.f, aS = 0.f, aP = 0.f;
#pragma unroll
        for (int mf = 0; mf < 4; ++mf) {
            const int jbase = jb0 + mf * 16;
#pragma unroll
            for (int reg = 0; reg < 4; ++reg) {
                const int b = nf * 16 + mf * 4 + reg;
                float pmv = ((pD >> b) & 1ull) ? 1.0f : 0.0f;
                float nmv = ((nD >> b) & 1ull) ? 1.0f : 0.0f;
                if (grow == jbase + reg) { pmv = 0.f; nmv = 0.f; }  // diagonal
                float v = acc[mf][nf][reg];
                float e = __builtin_amdgcn_exp2f(v * 14.4269504089f); // e^(10v)
                aN = fmaf(nmv, e, aN);
                aS = fmaf(pmv, v, aS);       // raw acc units; x10 in final_k
                aP += pmv;
            }
        }
        aN += __shfl_xor(aN, 16, 64);  aN += __shfl_xor(aN, 32, 64);
        aS += __shfl_xor(aS, 16, 64);  aS += __shfl_xor(aS, 32, 64);
        aP += __shfl_xor(aP, 16, 64);  aP += __shfl_xor(aP, 32, 64);
        if (q == 0) {
            atomicAdd(&negG[grow], aN);
            atomicAdd(&sG[grow],   aS);
            atomicAdd(&pG[grow],   aP);
        }
    }

    // ---- mirror epilogue (rows j, mask[j][i]) -- off-diagonal blocks only --
    if (offDiag) {
        const int jl2 = t >> 3;              // 0..31: strip-local j row
        const int iseg = (t & 7) * 16;       // 16-float i segment
#pragma unroll
        for (int st = 0; st < 4; ++st) {
            __syncthreads();                 // strip buffer free
            if (wm == (st >> 1)) {           // waves owning this strip's j's
#pragma unroll
                for (int m2 = 0; m2 < 2; ++m2) {
                    const int mf = (st & 1) * 2 + m2;
#pragma unroll
                    for (int nf = 0; nf < 4; ++nf) {
                        const int i = wn * 64 + nf * 16 + cl;
#pragma unroll
                        for (int reg = 0; reg < 4; ++reg) {
                            const int jl = m2 * 16 + q * 4 + reg;
                            T[jl * TSTRIDE + i] = acc[mf][nf][reg];
                        }
                    }
                }
            }
            __syncthreads();
            const int jg = colBase + st * 32 + jl2;
            const f4* tv = (const f4*)(T + jl2 * TSTRIDE + iseg);
            float aN = 0.f, aS = 0.f, aP = 0.f;
#pragma unroll
            for (int u = 0; u < 4; ++u) {
                f4 v4 = tv[u];
#pragma unroll
                for (int e = 0; e < 4; ++e) {
                    const int b = st * 16 + u * 4 + e;
                    float v = v4[e];
                    float pmv = ((pM >> b) & 1ull) ? 1.0f : 0.0f;
                    float nmv = ((nM >> b) & 1ull) ? 1.0f : 0.0f;
                    float ex = __builtin_amdgcn_exp2f(v * 14.4269504089f);
                    aN = fmaf(nmv, ex, aN);
                    aS = fmaf(pmv, v, aS);
                    aP += pmv;
                }
            }
            aN += __shfl_xor(aN, 1, 64); aN += __shfl_xor(aN, 2, 64); aN += __shfl_xor(aN, 4, 64);
            aS += __shfl_xor(aS, 1, 64); aS += __shfl_xor(aS, 2, 64); aS += __shfl_xor(aS, 4, 64);
            aP += __shfl_xor(aP, 1, 64); aP += __shfl_xor(aP, 2, 64); aP += __shfl_xor(aP, 4, 64);
            if ((t & 7) == 0) {
                atomicAdd(&negG[jg], aN);
                atomicAdd(&sG[jg],   aS);
                atomicAdd(&pG[jg],   aP);
            }
        }
    }
}

// ---------------------------------------------------------------------------
// Kernel 3: per-row loss assembly + mean
// loss_i = (P*log(neg) - 10*S_raw)/P (P>0 else 0);  out = mean
// ---------------------------------------------------------------------------
__global__ __launch_bounds__(1024) void final_k(const float* __restrict__ negG,
        const float* __restrict__ sG, const float* __restrict__ pG,
        float* __restrict__ out) {
    const int t = threadIdx.x;
    float sum = 0.f;
    for (int i = t; i < NROWS; i += 1024) {
        float P = pG[i];
        if (P > 0.f) {
            sum += (P * logf(negG[i]) - 10.0f * sG[i]) / P;
        }
    }
#pragma unroll
    for (int m = 32; m; m >>= 1) sum += __shfl_xor(sum, m, 64);
    __shared__ float wsum[16];
    if ((t & 63) == 0) wsum[t >> 6] = sum;
    __syncthreads();
    if (t < 16) {
        float v = wsum[t];
#pragma unroll
        for (int m = 8; m; m >>= 1) v += __shfl_xor(v, m, 16);
        if (t == 0) out[0] = v / (float)NROWS;
    }
}

// ---------------------------------------------------------------------------
extern "C" void kernel_launch(void* const* d_in, const int* in_sizes, int n_in,
                              void* d_out, int out_size, void* d_ws, size_t ws_size,
                              hipStream_t stream) {
    const float* feat  = (const float*)d_in[0];
    const float* pmask = (const float*)d_in[1];
    const float* nmask = (const float*)d_in[2];
    float* out = (float*)d_out;

    char* ws = (char*)d_ws;
    __hip_bfloat16* fn = (__hip_bfloat16*)ws;                    // 12,582,912 B
    float* negG = (float*)(ws + 12582912);
    float* sG = negG + NROWS;
    float* pG = sG + NROWS;

    // zero all three row accumulators (ws is re-poisoned before every launch)
    hipMemsetAsync(negG, 0, 3 * NROWS * sizeof(float), stream);

    normalize_k<<<NROWS, 256, 0, stream>>>(feat, fn);

    ntxent_main<<<2080, 256, 0, stream>>>(fn, pmask, nmask, negG, sG, pG);

    final_k<<<1, 1024, 0, stream>>>(negG, sG, pG, out);
}

// Round 3
// 626.441 us; speedup vs baseline: 1.0278x; 1.0278x over previous
//
#include <hip/hip_runtime.h>
#include <hip/hip_bf16.h>

#define NROWS 8192
#define DDIM 768

typedef short short8 __attribute__((ext_vector_type(8)));   // 8 x bf16 (4 VGPRs)
typedef float floatx4 __attribute__((ext_vector_type(4)));  // MFMA C/D
typedef float f4 __attribute__((ext_vector_type(4)));
#define TSTRIDE 132   // transpose LDS row stride (floats): 2-way banks, 16B aligned

// ---------------------------------------------------------------------------
// Kernel 1: row-normalize features (fp32 in) -> bf16 normalized rows
// ---------------------------------------------------------------------------
__global__ __launch_bounds__(256) void normalize_k(const float* __restrict__ f,
                                                   __hip_bfloat16* __restrict__ fn) {
    const int row = blockIdx.x;
    const int t = threadIdx.x;
    const float* fr = f + (size_t)row * DDIM;
    float v0 = fr[t];
    float v1 = fr[t + 256];
    float v2 = fr[t + 512];
    float ss = v0 * v0 + v1 * v1 + v2 * v2;
#pragma unroll
    for (int m = 32; m; m >>= 1) ss += __shfl_xor(ss, m, 64);
    __shared__ float wsum[4];
    if ((t & 63) == 0) wsum[t >> 6] = ss;
    __syncthreads();
    float tot = wsum[0] + wsum[1] + wsum[2] + wsum[3];
    float inv = 1.0f / fmaxf(sqrtf(tot), 1e-8f);
    __hip_bfloat16* o = fn + (size_t)row * DDIM;
    o[t]       = __float2bfloat16(v0 * inv);
    o[t + 256] = __float2bfloat16(v1 * inv);
    o[t + 512] = __float2bfloat16(v2 * inv);
}

// ---------------------------------------------------------------------------
// Kernel 2: SYMMETRIC bf16 GEMM (s = 10 * fn fn^T) + fused mask reductions.
// R11: in-K-loop mask streaming, slab version. R10 proved the overlap works
// (HBM bw rose) but paid +226 MB line fragmentation and +45 us of per-quad
// address VALU. Now: per K-iter, DMA up to 3 contiguous 8-row x 512-B mask
// slabs (full cache lines, consumed same round) into a 12 KB LDS slot;
// after the MFMA cluster the 64 owning threads of those rows bit-pack their
// 16 elements each (shift/mask addressing only) into pD/nD/pM/nM.
// Epilogues consume bits (R10's verified versions) -> zero epilogue HBM.
// K-loop sync = R8 two-barrier form (R9 showed counted-vmcnt neutral).
// ---------------------------------------------------------------------------
__global__ __launch_bounds__(256, 4) void ntxent_main(
        const __hip_bfloat16* __restrict__ fn,
        const float* __restrict__ pmask, const float* __restrict__ nmask,
        float* __restrict__ negG, float* __restrict__ sG,
        float* __restrict__ pG) {
    __shared__ __align__(16) char smem[28672];   // fn 16384 + mask slab 12288
    __hip_bfloat16* Is = (__hip_bfloat16*)smem;             // [128*32] bf16
    __hip_bfloat16* Js = Is + 128 * 32;
    char* maskLds = smem + 16384;                           // 3 x 4 KB slab slots
    float* T = (float*)smem;                                // mirror transpose alias

    const int t = threadIdx.x;
    const int lane = t & 63;
    const int wv = t >> 6;
    const int wm = wv & 1;           // wave's j-half
    const int wn = wv >> 1;          // wave's i-half
    const int q  = lane >> 4;
    const int cl = lane & 15;

    // XCD-chunked swizzle (2080 = 8*260, bijective)
    const int bt0 = blockIdx.x;
    const int bt = (bt0 & 7) * 260 + (bt0 >> 3);

    // triangular decode: block bt -> (c, r) with c <= r
    int r = (int)((sqrtf(8.0f * (float)bt + 1.0f) - 1.0f) * 0.5f);
    while ((r + 1) * (r + 2) / 2 <= bt) ++r;
    while (r * (r + 1) / 2 > bt) --r;
    const int c = bt - r * (r + 1) / 2;
    const int rowBase = c * 128;     // i-tile
    const int colBase = r * 128;     // j-tile
    const bool offDiag = (c != r);

    const int rdSw = ((q ^ ((cl >> 1) & 3)) << 4);

    // mask DMA per-thread constants: row-in-slab, col (floats)
    const int dmaRow8 = t >> 5;          // 0..7
    const int dmaCol  = (t & 31) * 4;    // 0..124

    floatx4 acc[4][4];            // [mf (j)][nf (i)]
#pragma unroll
    for (int mf = 0; mf < 4; ++mf)
#pragma unroll
        for (int nf = 0; nf < 4; ++nf)
            acc[mf][nf] = (floatx4){0.f, 0.f, 0.f, 0.f};

    // per-thread mask bits: direct (64) + mirror (64), pos & neg sides
    unsigned long long pD = 0ull, nD = 0ull, pM = 0ull, nM = 0ull;

    for (int kt = 0; kt < 24; ++kt) {
        const int k0 = kt * 32;
        __syncthreads();   // previous iter's readers done with Is/Js/maskLds

        // ---- mask slab DMA (HBM, line-contiguous): rounds g = kt*3+gl ----
#pragma unroll
        for (int gl = 0; gl < 3; ++gl) {
            const int g = kt * 3 + gl;
            if (g >= 64) break;                       // uniform
            const int side = g >> 5;                  // 0 direct, 1 mirror
            if (side && !offDiag) continue;           // uniform
            const int h = g & 31;
            const float* mp = (h & 1) ? nmask : pmask;
            const int rg = h >> 1;                    // 0..15: 8-row group
            const int rowG = (side ? colBase : rowBase) + rg * 8 + dmaRow8;
            const int colG = (side ? rowBase : colBase) + dmaCol;
            const float* src = mp + (size_t)rowG * NROWS + colG;
            __builtin_amdgcn_global_load_lds(
                (const __attribute__((address_space(1))) void*)src,
                (__attribute__((address_space(3))) void*)(maskLds + (gl * 256 + t) * 16),
                16, 0, 0);
        }

        // ---- fn staging (L2/L3-resident) ----
#pragma unroll
        for (int it = 0; it < 2; ++it) {
            const int s = it * 256 + t;              // 16B slot 0..511
            const int rr = s >> 2;
            const int cg = (s & 3) ^ ((rr >> 1) & 3); // swizzled src chunk
            const __hip_bfloat16* ga = fn + (size_t)(rowBase + rr) * DDIM + k0 + cg * 8;
            const __hip_bfloat16* gb = fn + (size_t)(colBase + rr) * DDIM + k0 + cg * 8;
            __builtin_amdgcn_global_load_lds(
                (const __attribute__((address_space(1))) void*)ga,
                (__attribute__((address_space(3))) void*)((char*)Is + s * 16), 16, 0, 0);
            __builtin_amdgcn_global_load_lds(
                (const __attribute__((address_space(1))) void*)gb,
                (__attribute__((address_space(3))) void*)((char*)Js + s * 16), 16, 0, 0);
        }
        __syncthreads();   // all DMA visible

        // ---- MFMA compute ----
        short8 jf[4], if_[4];
#pragma unroll
        for (int mf = 0; mf < 4; ++mf) {
            const int rr = wm * 64 + mf * 16 + cl;
            jf[mf] = *(const short8*)((const char*)Js + rr * 64 + rdSw);
        }
#pragma unroll
        for (int nf = 0; nf < 4; ++nf) {
            const int rr = wn * 64 + nf * 16 + cl;
            if_[nf] = *(const short8*)((const char*)Is + rr * 64 + rdSw);
        }
#pragma unroll
        for (int mf = 0; mf < 4; ++mf)
#pragma unroll
            for (int nf = 0; nf < 4; ++nf)
                acc[mf][nf] = __builtin_amdgcn_mfma_f32_16x16x32_bf16(
                    jf[mf], if_[nf], acc[mf][nf], 0, 0, 0);

        // ---- bit-pack this iter's slabs (owning threads only) ----
#pragma unroll
        for (int gl = 0; gl < 3; ++gl) {
            const int g = kt * 3 + gl;
            if (g >= 64) break;
            const int side = g >> 5;
            if (side && !offDiag) continue;
            const int h = g & 31;
            const bool isN = h & 1;
            const int rg = h >> 1;
            if (!side) {
                // direct rows r = rg*8 + rl; owner: wn==rg>>3, cl>>3==rg&1
                if ((t >> 7) == (rg >> 3) && (cl >> 3) == (rg & 1)) {
                    const int rl = cl & 7;
                    const int rloc = rg * 8 + rl;
                    const int nf = (rloc >> 4) & 3;
                    const char* base = maskLds + gl * 4096 + rl * 512
                                     + wm * 256 + q * 16;
                    unsigned long long add = 0ull;
#pragma unroll
                    for (int mf = 0; mf < 4; ++mf) {
                        const f4 m4 = *(const f4*)(base + mf * 64);
                        const int bb = nf * 16 + mf * 4;
#pragma unroll
                        for (int e = 0; e < 4; ++e)
                            add |= (m4[e] > 0.5f) ? (1ull << (bb + e)) : 0ull;
                    }
                    if (!isN) pD |= add; else nD |= add;
                }
            } else {
                // mirror rows m = rg*8 + rl; owner wave: wv == rg&3
                if (wv == (rg & 3)) {
                    const int rl = (t >> 3) & 7;
                    const int st = rg >> 2;
                    const char* base = maskLds + gl * 4096 + rl * 512
                                     + (t & 7) * 64;
                    unsigned long long add = 0ull;
#pragma unroll
                    for (int u = 0; u < 4; ++u) {
                        const f4 m4 = *(const f4*)(base + u * 16);
                        const int bb = st * 16 + u * 4;
#pragma unroll
                        for (int e = 0; e < 4; ++e)
                            add |= (m4[e] > 0.5f) ? (1ull << (bb + e)) : 0ull;
                    }
                    if (!isN) pM |= add; else nM |= add;
                }
            }
        }
    }

    // ---- direct epilogue (rows i, mask[i][j]) -- masks from bits ----
    const int col64 = colBase + wm * 64;
    const int jb0 = col64 + q * 4;
#pragma unroll
    for (int nf = 0; nf < 4; ++nf) {
        const int grow = rowBase + wn * 64 + nf * 16 + cl;
        float aN = 0.f, aS = 0.f, aP = 0.f;
#pragma unroll
        for (int mf = 0; mf < 4; ++mf) {
            const int jbase = jb0 + mf * 16;
#pragma unroll
            for (int reg = 0; reg < 4; ++reg) {
                const int b = nf * 16 + mf * 4 + reg;
                float pmv = ((pD >> b) & 1ull) ? 1.0f : 0.0f;
                float nmv = ((nD >> b) & 1ull) ? 1.0f : 0.0f;
                if (grow == jbase + reg) { pmv = 0.f; nmv = 0.f; }  // diagonal
                float v = acc[mf][nf][reg];
                float e = __builtin_amdgcn_exp2f(v * 14.4269504089f); // e^(10v)
                aN = fmaf(nmv, e, aN);
                aS = fmaf(pmv, v, aS);       // raw acc units; x10 in final_k
                aP += pmv;
            }
        }
        aN += __shfl_xor(aN, 16, 64);  aN += __shfl_xor(aN, 32, 64);
        aS += __shfl_xor(aS, 16, 64);  aS += __shfl_xor(aS, 32, 64);
        aP += __shfl_xor(aP, 16, 64);  aP += __shfl_xor(aP, 32, 64);
        if (q == 0) {
            atomicAdd(&negG[grow], aN);
            atomicAdd(&sG[grow],   aS);
            atomicAdd(&pG[grow],   aP);
        }
    }

    // ---- mirror epilogue (rows j, mask[j][i]) -- off-diagonal blocks only --
    if (offDiag) {
        const int jl2 = t >> 3;              // 0..31: strip-local j row
        const int iseg = (t & 7) * 16;       // 16-float i segment
#pragma unroll
        for (int st = 0; st < 4; ++st) {
            __syncthreads();                 // strip buffer free
            if (wm == (st >> 1)) {           // waves owning this strip's j's
#pragma unroll
                for (int m2 = 0; m2 < 2; ++m2) {
                    const int mf = (st & 1) * 2 + m2;
#pragma unroll
                    for (int nf = 0; nf < 4; ++nf) {
                        const int i = wn * 64 + nf * 16 + cl;
#pragma unroll
                        for (int reg = 0; reg < 4; ++reg) {
                            const int jl = m2 * 16 + q * 4 + reg;
                            T[jl * TSTRIDE + i] = acc[mf][nf][reg];
                        }
                    }
                }
            }
            __syncthreads();
            const int jg = colBase + st * 32 + jl2;
            const f4* tv = (const f4*)(T + jl2 * TSTRIDE + iseg);
            float aN = 0.f, aS = 0.f, aP = 0.f;
#pragma unroll
            for (int u = 0; u < 4; ++u) {
                f4 v4 = tv[u];
#pragma unroll
                for (int e = 0; e < 4; ++e) {
                    const int b = st * 16 + u * 4 + e;
                    float v = v4[e];
                    float pmv = ((pM >> b) & 1ull) ? 1.0f : 0.0f;
                    float nmv = ((nM >> b) & 1ull) ? 1.0f : 0.0f;
                    float ex = __builtin_amdgcn_exp2f(v * 14.4269504089f);
                    aN = fmaf(nmv, ex, aN);
                    aS = fmaf(pmv, v, aS);
                    aP += pmv;
                }
            }
            aN += __shfl_xor(aN, 1, 64); aN += __shfl_xor(aN, 2, 64); aN += __shfl_xor(aN, 4, 64);
            aS += __shfl_xor(aS, 1, 64); aS += __shfl_xor(aS, 2, 64); aS += __shfl_xor(aS, 4, 64);
            aP += __shfl_xor(aP, 1, 64); aP += __shfl_xor(aP, 2, 64); aP += __shfl_xor(aP, 4, 64);
            if ((t & 7) == 0) {
                atomicAdd(&negG[jg], aN);
                atomicAdd(&sG[jg],   aS);
                atomicAdd(&pG[jg],   aP);
            }
        }
    }
}

// ---------------------------------------------------------------------------
// Kernel 3: per-row loss assembly + mean
// loss_i = (P*log(neg) - 10*S_raw)/P (P>0 else 0);  out = mean
// ---------------------------------------------------------------------------
__global__ __launch_bounds__(1024) void final_k(const float* __restrict__ negG,
        const float* __restrict__ sG, const float* __restrict__ pG,
        float* __restrict__ out) {
    const int t = threadIdx.x;
    float sum = 0.f;
    for (int i = t; i < NROWS; i += 1024) {
        float P = pG[i];
        if (P > 0.f) {
            sum += (P * logf(negG[i]) - 10.0f * sG[i]) / P;
        }
    }
#pragma unroll
    for (int m = 32; m; m >>= 1) sum += __shfl_xor(sum, m, 64);
    __shared__ float wsum[16];
    if ((t & 63) == 0) wsum[t >> 6] = sum;
    __syncthreads();
    if (t < 16) {
        float v = wsum[t];
#pragma unroll
        for (int m = 8; m; m >>= 1) v += __shfl_xor(v, m, 16);
        if (t == 0) out[0] = v / (float)NROWS;
    }
}

// ---------------------------------------------------------------------------
extern "C" void kernel_launch(void* const* d_in, const int* in_sizes, int n_in,
                              void* d_out, int out_size, void* d_ws, size_t ws_size,
                              hipStream_t stream) {
    const float* feat  = (const float*)d_in[0];
    const float* pmask = (const float*)d_in[1];
    const float* nmask = (const float*)d_in[2];
    float* out = (float*)d_out;

    char* ws = (char*)d_ws;
    __hip_bfloat16* fn = (__hip_bfloat16*)ws;                    // 12,582,912 B
    float* negG = (float*)(ws + 12582912);
    float* sG = negG + NROWS;
    float* pG = sG + NROWS;

    // zero all three row accumulators (ws is re-poisoned before every launch)
    hipMemsetAsync(negG, 0, 3 * NROWS * sizeof(float), stream);

    normalize_k<<<NROWS, 256, 0, stream>>>(feat, fn);

    ntxent_main<<<2080, 256, 0, stream>>>(fn, pmask, nmask, negG, sG, pG);

    final_k<<<1, 1024, 0, stream>>>(negG, sG, pG, out);
}